// Round 6
// baseline (486.620 us; speedup 1.0000x reference)
//
#include <hip/hip_runtime.h>
#include <stdint.h>
#include <stddef.h>

// Problem constants
#define T_SEQ 2048
#define C_DIM 640
#define N_BATCH 8

typedef __bf16 bf16x8 __attribute__((ext_vector_type(8)));
typedef float f32x4 __attribute__((ext_vector_type(4)));

__device__ __forceinline__ unsigned short f2bf(float f) {
  unsigned u = __float_as_uint(f);
  u += 0x7fffu + ((u >> 16) & 1u);   // round-to-nearest-even
  return (unsigned short)(u >> 16);
}
__device__ __forceinline__ float bf2f(unsigned short h) {
  return __uint_as_float(((unsigned)h) << 16);
}

__device__ __forceinline__ void gll16(const unsigned short* src, unsigned short* dst) {
  __builtin_amdgcn_global_load_lds(
      (const __attribute__((address_space(1))) void*)src,
      (__attribute__((address_space(3))) void*)dst, 16, 0, 0);
}

// Stage a 128(rows) x 64(k) bf16 tile into LDS (linear dest, row stride 128B).
// Global source pre-swizzled (rule #21) so swizzled ds_reads (byte ^= (row&7)<<4)
// observe logical data.
__device__ __forceinline__ void stage_tile(const unsigned short* gbase, int ldg,
                                           unsigned short* lbuf, int wave, int lane) {
#pragma unroll
  for (int i = 0; i < 4; ++i) {
    const int o   = i * 4096 + wave * 1024 + lane * 16;  // byte offset in tile
    const int row = o >> 7;
    const int cb  = o & 127;
    const int scb = cb ^ ((row & 7) << 4);               // involution within row
    const unsigned short* src = gbase + (size_t)row * ldg + (scb >> 1);
    unsigned short* dst = lbuf + ((i * 4096 + wave * 1024) >> 1);  // wave-uniform
    gll16(src, dst);
  }
}

// Decode t in [0,136) -> (mi, ni) with t = mi(mi+1)/2 + ni, ni<=mi.
__device__ __forceinline__ void tri_decode(int t, int& mi, int& ni) {
  int m = (int)((__fsqrt_rn(8.0f * (float)t + 1.0f) - 1.0f) * 0.5f);
  while ((m + 1) * (m + 2) / 2 <= t) ++m;
  while (m * (m + 1) / 2 > t) --m;
  mi = m;
  ni = t - m * (m + 1) / 2;
}

// One GEMM, three uses (all operands "row-major, K-contiguous" i.e. B^T layout):
// MODE 0: QKV projection. A=xb(16384x640), B=wb[z](640x640), out bf16 Q/K/V.
// MODE 1: S=QK^T per batch (causal tiles), epilogue: P=exp(S) masked, bf16, +Lpart.
//         No max-subtraction: scores ~N(0,1) (wq carries 1/sqrt(C)), exp <= ~e^6.
// MODE 2: out = P V^T_t / L + x. A=P_b(2048x2048), B=Vt_b(640x2048), out fp32.
// 128x128 tile, BK=64, 4 waves (2x2), mfma_f32_16x16x32_bf16, acc 4x4 frags/wave.
//
// m97 STRUCTURE (this round's change): SINGLE-buffered 32 KB LDS, two barriers
// per K-step ({stage -> sync -> compute -> sync}). Latency hiding comes from
// 5 co-resident blocks/CU (LDS 5x32=160 KB, VGPR 88<=102), not intra-block
// prefetch — m97 measured 874-912 TF vs our double-buffered 740, and full
// residency (1280 block slots) dissolves grid-quantization tails.
// Linear grid + XCD-chunk swizzle (T1); A-tile sharers adjacent.
template <int MODE>
__global__ __launch_bounds__(256, 5) void gemm_k(
    const unsigned short* __restrict__ Abase, const unsigned short* __restrict__ Bbase,
    unsigned short* __restrict__ OutB, float* __restrict__ OutF,
    const float* __restrict__ Lrow, const float* __restrict__ Xres,
    float* __restrict__ Lpart) {
  const int lin = blockIdx.x;
  int mi, ni, bz;
  if constexpr (MODE == 0) {
    // nwg = 1920 = 8 * 240; logical wg = mi*15 + (z*5 + ni)
    const int wg = (lin & 7) * 240 + (lin >> 3);
    mi = wg / 15;
    const int t = wg % 15;
    bz = t / 5;            // weight index z
    ni = t % 5;
  } else if constexpr (MODE == 1) {
    // nwg = 1088 = 8 * 136; XCD k == batch k
    const int wg = (lin & 7) * 136 + (lin >> 3);
    bz = wg / 136;
    tri_decode(wg % 136, mi, ni);
  } else {
    // nwg = 640 = 8 * 80; heavy row-blocks (long K) dispatched first
    const int wg = (lin & 7) * 80 + (lin >> 3);
    bz = wg / 80;
    const int t = wg % 80;
    mi = 15 - t / 5;
    ni = t % 5;
  }

  __shared__ unsigned short As[8192];  // 128x64 bf16, single-buffered (16 KB)
  __shared__ unsigned short Bs[8192];
  const int tid = threadIdx.x;
  const int wave = tid >> 6, lane = tid & 63;
  const int wm = wave >> 1, wn = wave & 1;

  const unsigned short* Ap;
  const unsigned short* Bp;
  int ldA, ldB, ksteps;
  if constexpr (MODE == 0) {
    Ap = Abase + (size_t)mi * 128 * 640;
    Bp = Bbase + (size_t)bz * 409600 + (size_t)ni * 128 * 640;
    ldA = 640; ldB = 640; ksteps = 10;
  } else if constexpr (MODE == 1) {
    Ap = Abase + (size_t)bz * 1310720 + (size_t)mi * 128 * 640;
    Bp = Bbase + (size_t)bz * 1310720 + (size_t)ni * 128 * 640;
    ldA = 640; ldB = 640; ksteps = 10;
  } else {
    Ap = Abase + (size_t)bz * 4194304 + (size_t)mi * 128 * 2048;
    Bp = Bbase + (size_t)bz * 1310720 + (size_t)ni * 128 * 2048;
    ldA = 2048; ldB = 2048; ksteps = 2 * (mi + 1);  // causal K bound
  }

  f32x4 acc[4][4] = {};

  for (int t = 0; t < ksteps; ++t) {
    stage_tile(Ap + (size_t)t * 64, ldA, As, wave, lane);
    stage_tile(Bp + (size_t)t * 64, ldB, Bs, wave, lane);
    __syncthreads();  // vmcnt(0) drain: tile t visible to all waves
#pragma unroll
    for (int kk = 0; kk < 2; ++kk) {
      bf16x8 af[4], bfr[4];
#pragma unroll
      for (int mt = 0; mt < 4; ++mt) {
        const int row = wm * 64 + mt * 16 + (lane & 15);
        const int cb  = kk * 64 + ((lane >> 4) << 4);
        af[mt] = *(const bf16x8*)&As[row * 64 + ((cb ^ ((row & 7) << 4)) >> 1)];
      }
#pragma unroll
      for (int nt = 0; nt < 4; ++nt) {
        const int row = wn * 64 + nt * 16 + (lane & 15);
        const int cb  = kk * 64 + ((lane >> 4) << 4);
        bfr[nt] = *(const bf16x8*)&Bs[row * 64 + ((cb ^ ((row & 7) << 4)) >> 1)];
      }
#pragma unroll
      for (int mt = 0; mt < 4; ++mt)
#pragma unroll
        for (int nt = 0; nt < 4; ++nt)
          acc[mt][nt] = __builtin_amdgcn_mfma_f32_16x16x32_bf16(af[mt], bfr[nt],
                                                                acc[mt][nt], 0, 0, 0);
    }
    if (t + 1 < ksteps) __syncthreads();  // all waves done reading before restage
  }

  // Epilogue. C/D frag: col = lane&15, row = (lane>>4)*4 + r  [m89/m91-verified]
  if constexpr (MODE == 1) {
    // P = exp(S) with causal mask; per-row partial sums -> Lpart[row][ni*2+wn].
#pragma unroll
    for (int mt = 0; mt < 4; ++mt) {
      const int r0 = wm * 64 + mt * 16 + ((lane >> 4) << 2);
      const int grow = mi * 128 + r0;
      float rsum[4] = {0.f, 0.f, 0.f, 0.f};
#pragma unroll
      for (int nt = 0; nt < 4; ++nt) {
        const int gc = ni * 128 + wn * 64 + nt * 16 + (lane & 15);
        const size_t base = (size_t)bz * 4194304 + (size_t)grow * 2048 + gc;
#pragma unroll
        for (int r = 0; r < 4; ++r) {
          const float e = (gc <= grow + r) ? __expf(acc[mt][nt][r]) : 0.0f;
          OutB[base + (size_t)r * 2048] = f2bf(e);
          rsum[r] += e;
        }
      }
#pragma unroll
      for (int off = 1; off < 16; off <<= 1) {
#pragma unroll
        for (int r = 0; r < 4; ++r) rsum[r] += __shfl_xor(rsum[r], off);
      }
      if ((lane & 15) == 0) {
#pragma unroll
        for (int r = 0; r < 4; ++r)
          Lpart[((size_t)bz * 2048 + grow + r) * 32 + ni * 2 + wn] = rsum[r];
      }
    }
  } else {
#pragma unroll
    for (int mt = 0; mt < 4; ++mt) {
#pragma unroll
      for (int nt = 0; nt < 4; ++nt) {
        const int r0 = wm * 64 + mt * 16 + ((lane >> 4) << 2);
        const int c  = wn * 64 + nt * 16 + (lane & 15);
        if constexpr (MODE == 0) {
          const size_t base = (size_t)bz * 10485760 + (size_t)(mi * 128 + r0) * 640 + ni * 128 + c;
#pragma unroll
          for (int r = 0; r < 4; ++r) OutB[base + (size_t)r * 640] = f2bf(acc[mt][nt][r]);
        } else {
          const int grow = mi * 128 + r0;
          const size_t base = (size_t)bz * 1310720 + (size_t)grow * 640 + ni * 128 + c;
#pragma unroll
          for (int r = 0; r < 4; ++r) {
            const float l = Lrow[(size_t)bz * 2048 + grow + r];
            OutF[base + (size_t)r * 640] = acc[mt][nt][r] / l + Xres[base + (size_t)r * 640];
          }
        }
      }
    }
  }
}

__global__ void cast_x_k(const float* __restrict__ x, unsigned short* __restrict__ xb, int n4) {
  const int stride = gridDim.x * blockDim.x;
  for (int i = blockIdx.x * blockDim.x + threadIdx.x; i < n4; i += stride) {
    const float4 v = ((const float4*)x)[i];
    ushort4 o;
    o.x = f2bf(v.x); o.y = f2bf(v.y); o.z = f2bf(v.z); o.w = f2bf(v.w);
    ((ushort4*)xb)[i] = o;
  }
}

// w_q gets the 1/sqrt(C) softmax scale folded in.
__global__ void cast_w_k(const float* __restrict__ wq, const float* __restrict__ wk,
                         const float* __restrict__ wv, unsigned short* __restrict__ wb) {
  const int z = blockIdx.y;
  const float* w = (z == 0) ? wq : ((z == 1) ? wk : wv);
  const float s = (z == 0) ? 0.03952847075210474f : 1.0f;  // 1/sqrt(640)
  const int i = blockIdx.x * 256 + threadIdx.x;             // 400 blocks * 256 * 4 = 409600
  const float4 v = ((const float4*)w)[i];
  ushort4 o;
  o.x = f2bf(v.x * s); o.y = f2bf(v.y * s); o.z = f2bf(v.z * s); o.w = f2bf(v.w * s);
  ((ushort4*)(wb + (size_t)z * 409600))[i] = o;
}

// V (b,t,c) -> Vt (b,c,t) so PV's B-operand is K-contiguous.
__global__ void transpose_v(const unsigned short* __restrict__ V,
                            unsigned short* __restrict__ Vt) {
  __shared__ unsigned short tile[32][33];
  const int t0 = blockIdx.x * 32, c0 = blockIdx.y * 32, b = blockIdx.z;
  const unsigned short* Vb = V + (size_t)b * T_SEQ * C_DIM;
  unsigned short* Vtb = Vt + (size_t)b * C_DIM * T_SEQ;
  const int tx = threadIdx.x, ty = threadIdx.y;
#pragma unroll
  for (int i = 0; i < 4; ++i)
    tile[ty + i * 8][tx] = Vb[(size_t)(t0 + ty + i * 8) * C_DIM + c0 + tx];
  __syncthreads();
#pragma unroll
  for (int i = 0; i < 4; ++i)
    Vtb[(size_t)(c0 + ty + i * 8) * T_SEQ + t0 + tx] = tile[tx][ty + i * 8];
}

// L[row] = sum over written Lpart entries (j < 2*(miR+1)); deterministic order.
__global__ void rowsum_k(const float* __restrict__ Lpart, float* __restrict__ Lr) {
  const int i = blockIdx.x * 256 + threadIdx.x;  // 64 blocks x 256 = 16384 rows
  const int jmax = (((i & 2047) >> 7) + 1) * 2;
  const float* p = Lpart + (size_t)i * 32;
  float s = 0.f;
  for (int j = 0; j < jmax; ++j) s += p[j];
  Lr[i] = s;
}

extern "C" void kernel_launch(void* const* d_in, const int* in_sizes, int n_in,
                              void* d_out, int out_size, void* d_ws, size_t ws_size,
                              hipStream_t stream) {
  (void)in_sizes; (void)n_in; (void)out_size; (void)ws_size;
  const float* x  = (const float*)d_in[0];
  const float* wq = (const float*)d_in[1];
  const float* wk = (const float*)d_in[2];
  const float* wv = (const float*)d_in[3];
  float* out = (float*)d_out;

  // Workspace layout (bytes); total 174,489,600 B (proven-safe bound)
  char* ws = (char*)d_ws;
  unsigned short* xb = (unsigned short*)(ws + 0);          // 16384x640 bf16
  float*          Lpart = (float*)(ws + 0);                // 16384x32 fp32, ALIASES xb
                                                            // (xb dead after gemm<0>)
  unsigned short* wb = (unsigned short*)(ws + 20971520);   // 3x640x640 bf16 (wq scaled)
  unsigned short* Qb = (unsigned short*)(ws + 23429120);   // Q,K,V contiguous bf16
  unsigned short* Vt = (unsigned short*)(ws + 86343680);   // 8x640x2048 bf16
  float*          Lr = (float*)(ws + 107315200);           // 16384 fp32 row sums
  unsigned short* Sb = (unsigned short*)(ws + 107380736);  // 8x2048x2048 bf16 (P)

  cast_x_k<<<2048, 256, 0, stream>>>(x, xb, 2621440);
  cast_w_k<<<dim3(400, 3), 256, 0, stream>>>(wq, wk, wv, wb);
  // QKV projections: 1920 linear blocks, XCD-swizzled, A-tile shared by 15 adjacent
  gemm_k<0><<<1920, 256, 0, stream>>>(xb, wb, Qb, nullptr, nullptr, nullptr, nullptr);
  transpose_v<<<dim3(64, 20, 8), dim3(32, 8), 0, stream>>>(Qb + (size_t)2 * 10485760, Vt);
  // P = exp(QK^T) causal (fused, unnormalized) + Lpart: 1088 blocks, batch per XCD
  gemm_k<1><<<1088, 256, 0, stream>>>(Qb, Qb + 10485760, Sb, nullptr, nullptr, nullptr,
                                      Lpart);
  rowsum_k<<<64, 256, 0, stream>>>(Lpart, Lr);
  // out = P Vt / L + x: 640 blocks, batch per XCD, heavy rows first
  gemm_k<2><<<640, 256, 0, stream>>>(Sb, Vt, nullptr, out, Lr, x, nullptr);
}

// Round 7
// 171.634 us; speedup vs baseline: 2.8352x; 2.8352x over previous
//
#include <hip/hip_runtime.h>
#include <stdint.h>
#include <stddef.h>

// Problem constants
#define T_SEQ 2048
#define C_DIM 640
#define N_BATCH 8

typedef __bf16 bf16x8 __attribute__((ext_vector_type(8)));
typedef float f32x4 __attribute__((ext_vector_type(4)));

__device__ __forceinline__ unsigned short f2bf(float f) {
  unsigned u = __float_as_uint(f);
  u += 0x7fffu + ((u >> 16) & 1u);   // round-to-nearest-even
  return (unsigned short)(u >> 16);
}
__device__ __forceinline__ float bf2f(unsigned short h) {
  return __uint_as_float(((unsigned)h) << 16);
}

__device__ __forceinline__ void gll16(const unsigned short* src, unsigned short* dst) {
  __builtin_amdgcn_global_load_lds(
      (const __attribute__((address_space(1))) void*)src,
      (__attribute__((address_space(3))) void*)dst, 16, 0, 0);
}

// Stage a 128(rows) x 64(k) bf16 tile into LDS (linear dest, row stride 128B).
// Global source pre-swizzled (rule #21) so swizzled ds_reads (byte ^= (row&7)<<4)
// observe logical data.
__device__ __forceinline__ void stage_tile(const unsigned short* gbase, int ldg,
                                           unsigned short* lbuf, int wave, int lane) {
#pragma unroll
  for (int i = 0; i < 4; ++i) {
    const int o   = i * 4096 + wave * 1024 + lane * 16;  // byte offset in tile
    const int row = o >> 7;
    const int cb  = o & 127;
    const int scb = cb ^ ((row & 7) << 4);               // involution within row
    const unsigned short* src = gbase + (size_t)row * ldg + (scb >> 1);
    unsigned short* dst = lbuf + ((i * 4096 + wave * 1024) >> 1);  // wave-uniform
    gll16(src, dst);
  }
}

// Decode t in [0,136) -> (mi, ni) with t = mi(mi+1)/2 + ni, ni<=mi.
__device__ __forceinline__ void tri_decode(int t, int& mi, int& ni) {
  int m = (int)((__fsqrt_rn(8.0f * (float)t + 1.0f) - 1.0f) * 0.5f);
  while ((m + 1) * (m + 2) / 2 <= t) ++m;
  while (m * (m + 1) / 2 > t) --m;
  mi = m;
  ni = t - m * (m + 1) / 2;
}

// One GEMM, three uses (all operands "row-major, K-contiguous" i.e. B^T layout):
// MODE 0: QKV projection. A=xb(16384x640), B=wb[z](640x640), out bf16 Q/K/V.
// MODE 1: S=QK^T per batch (causal tiles), epilogue: P=exp(S) masked, bf16, +Lpart.
//         No max-subtraction: scores ~N(0,1) (wq carries 1/sqrt(C)), exp <= ~e^6.
// MODE 2: out = P V^T_t / L + x. A=P_b(2048x2048), B=Vt_b(640x2048), out fp32.
// 128x128 tile, BK=64, 4 waves (2x2), mfma_f32_16x16x32_bf16, acc 4x4 frags/wave.
//
// m97 structure: SINGLE-buffered 32 KB LDS, two barriers per K-step. Latency
// hiding via multiple co-resident blocks/CU. NO second launch_bounds arg:
// round 6 proved forcing 5 blocks/CU makes the allocator cut VGPR 88->48,
// spilling the 64-reg accumulator to scratch (WRITE_SIZE 41->386 MB, 2.3x
// slower). At natural 88 VGPR the per-SIMD pool (512) gives 5 waves/SIMD and
// 32 KB LDS gives 5 blocks/CU anyway.
// Linear grid + XCD-chunk swizzle (T1); A-tile sharers adjacent.
template <int MODE>
__global__ __launch_bounds__(256) void gemm_k(
    const unsigned short* __restrict__ Abase, const unsigned short* __restrict__ Bbase,
    unsigned short* __restrict__ OutB, float* __restrict__ OutF,
    const float* __restrict__ Lrow, const float* __restrict__ Xres,
    float* __restrict__ Lpart) {
  const int lin = blockIdx.x;
  int mi, ni, bz;
  if constexpr (MODE == 0) {
    // nwg = 1920 = 8 * 240; logical wg = mi*15 + (z*5 + ni)
    const int wg = (lin & 7) * 240 + (lin >> 3);
    mi = wg / 15;
    const int t = wg % 15;
    bz = t / 5;            // weight index z
    ni = t % 5;
  } else if constexpr (MODE == 1) {
    // nwg = 1088 = 8 * 136; XCD k == batch k
    const int wg = (lin & 7) * 136 + (lin >> 3);
    bz = wg / 136;
    tri_decode(wg % 136, mi, ni);
  } else {
    // nwg = 640 = 8 * 80; heavy row-blocks (long K) dispatched first
    const int wg = (lin & 7) * 80 + (lin >> 3);
    bz = wg / 80;
    const int t = wg % 80;
    mi = 15 - t / 5;
    ni = t % 5;
  }

  __shared__ unsigned short As[8192];  // 128x64 bf16, single-buffered (16 KB)
  __shared__ unsigned short Bs[8192];
  const int tid = threadIdx.x;
  const int wave = tid >> 6, lane = tid & 63;
  const int wm = wave >> 1, wn = wave & 1;

  const unsigned short* Ap;
  const unsigned short* Bp;
  int ldA, ldB, ksteps;
  if constexpr (MODE == 0) {
    Ap = Abase + (size_t)mi * 128 * 640;
    Bp = Bbase + (size_t)bz * 409600 + (size_t)ni * 128 * 640;
    ldA = 640; ldB = 640; ksteps = 10;
  } else if constexpr (MODE == 1) {
    Ap = Abase + (size_t)bz * 1310720 + (size_t)mi * 128 * 640;
    Bp = Bbase + (size_t)bz * 1310720 + (size_t)ni * 128 * 640;
    ldA = 640; ldB = 640; ksteps = 10;
  } else {
    Ap = Abase + (size_t)bz * 4194304 + (size_t)mi * 128 * 2048;
    Bp = Bbase + (size_t)bz * 1310720 + (size_t)ni * 128 * 2048;
    ldA = 2048; ldB = 2048; ksteps = 2 * (mi + 1);  // causal K bound
  }

  f32x4 acc[4][4] = {};

  for (int t = 0; t < ksteps; ++t) {
    stage_tile(Ap + (size_t)t * 64, ldA, As, wave, lane);
    stage_tile(Bp + (size_t)t * 64, ldB, Bs, wave, lane);
    __syncthreads();  // vmcnt(0) drain: tile t visible to all waves
#pragma unroll
    for (int kk = 0; kk < 2; ++kk) {
      bf16x8 af[4], bfr[4];
#pragma unroll
      for (int mt = 0; mt < 4; ++mt) {
        const int row = wm * 64 + mt * 16 + (lane & 15);
        const int cb  = kk * 64 + ((lane >> 4) << 4);
        af[mt] = *(const bf16x8*)&As[row * 64 + ((cb ^ ((row & 7) << 4)) >> 1)];
      }
#pragma unroll
      for (int nt = 0; nt < 4; ++nt) {
        const int row = wn * 64 + nt * 16 + (lane & 15);
        const int cb  = kk * 64 + ((lane >> 4) << 4);
        bfr[nt] = *(const bf16x8*)&Bs[row * 64 + ((cb ^ ((row & 7) << 4)) >> 1)];
      }
#pragma unroll
      for (int mt = 0; mt < 4; ++mt)
#pragma unroll
        for (int nt = 0; nt < 4; ++nt)
          acc[mt][nt] = __builtin_amdgcn_mfma_f32_16x16x32_bf16(af[mt], bfr[nt],
                                                                acc[mt][nt], 0, 0, 0);
    }
    if (t + 1 < ksteps) __syncthreads();  // all waves done reading before restage
  }

  // Epilogue. C/D frag: col = lane&15, row = (lane>>4)*4 + r  [m89/m91-verified]
  if constexpr (MODE == 1) {
    // P = exp(S) with causal mask; per-row partial sums -> Lpart[row][ni*2+wn].
#pragma unroll
    for (int mt = 0; mt < 4; ++mt) {
      const int r0 = wm * 64 + mt * 16 + ((lane >> 4) << 2);
      const int grow = mi * 128 + r0;
      float rsum[4] = {0.f, 0.f, 0.f, 0.f};
#pragma unroll
      for (int nt = 0; nt < 4; ++nt) {
        const int gc = ni * 128 + wn * 64 + nt * 16 + (lane & 15);
        const size_t base = (size_t)bz * 4194304 + (size_t)grow * 2048 + gc;
#pragma unroll
        for (int r = 0; r < 4; ++r) {
          const float e = (gc <= grow + r) ? __expf(acc[mt][nt][r]) : 0.0f;
          OutB[base + (size_t)r * 2048] = f2bf(e);
          rsum[r] += e;
        }
      }
#pragma unroll
      for (int off = 1; off < 16; off <<= 1) {
#pragma unroll
        for (int r = 0; r < 4; ++r) rsum[r] += __shfl_xor(rsum[r], off);
      }
      if ((lane & 15) == 0) {
#pragma unroll
        for (int r = 0; r < 4; ++r)
          Lpart[((size_t)bz * 2048 + grow + r) * 32 + ni * 2 + wn] = rsum[r];
      }
    }
  } else {
#pragma unroll
    for (int mt = 0; mt < 4; ++mt) {
#pragma unroll
      for (int nt = 0; nt < 4; ++nt) {
        const int r0 = wm * 64 + mt * 16 + ((lane >> 4) << 2);
        const int c  = wn * 64 + nt * 16 + (lane & 15);
        if constexpr (MODE == 0) {
          const size_t base = (size_t)bz * 10485760 + (size_t)(mi * 128 + r0) * 640 + ni * 128 + c;
#pragma unroll
          for (int r = 0; r < 4; ++r) OutB[base + (size_t)r * 640] = f2bf(acc[mt][nt][r]);
        } else {
          const int grow = mi * 128 + r0;
          const size_t base = (size_t)bz * 1310720 + (size_t)grow * 640 + ni * 128 + c;
#pragma unroll
          for (int r = 0; r < 4; ++r) {
            const float l = Lrow[(size_t)bz * 2048 + grow + r];
            OutF[base + (size_t)r * 640] = acc[mt][nt][r] / l + Xres[base + (size_t)r * 640];
          }
        }
      }
    }
  }
}

__global__ void cast_x_k(const float* __restrict__ x, unsigned short* __restrict__ xb, int n4) {
  const int stride = gridDim.x * blockDim.x;
  for (int i = blockIdx.x * blockDim.x + threadIdx.x; i < n4; i += stride) {
    const float4 v = ((const float4*)x)[i];
    ushort4 o;
    o.x = f2bf(v.x); o.y = f2bf(v.y); o.z = f2bf(v.z); o.w = f2bf(v.w);
    ((ushort4*)xb)[i] = o;
  }
}

// w_q gets the 1/sqrt(C) softmax scale folded in.
__global__ void cast_w_k(const float* __restrict__ wq, const float* __restrict__ wk,
                         const float* __restrict__ wv, unsigned short* __restrict__ wb) {
  const int z = blockIdx.y;
  const float* w = (z == 0) ? wq : ((z == 1) ? wk : wv);
  const float s = (z == 0) ? 0.03952847075210474f : 1.0f;  // 1/sqrt(640)
  const int i = blockIdx.x * 256 + threadIdx.x;             // 400 blocks * 256 * 4 = 409600
  const float4 v = ((const float4*)w)[i];
  ushort4 o;
  o.x = f2bf(v.x * s); o.y = f2bf(v.y * s); o.z = f2bf(v.z * s); o.w = f2bf(v.w * s);
  ((ushort4*)(wb + (size_t)z * 409600))[i] = o;
}

// V (b,t,c) -> Vt (b,c,t) so PV's B-operand is K-contiguous.
__global__ void transpose_v(const unsigned short* __restrict__ V,
                            unsigned short* __restrict__ Vt) {
  __shared__ unsigned short tile[32][33];
  const int t0 = blockIdx.x * 32, c0 = blockIdx.y * 32, b = blockIdx.z;
  const unsigned short* Vb = V + (size_t)b * T_SEQ * C_DIM;
  unsigned short* Vtb = Vt + (size_t)b * C_DIM * T_SEQ;
  const int tx = threadIdx.x, ty = threadIdx.y;
#pragma unroll
  for (int i = 0; i < 4; ++i)
    tile[ty + i * 8][tx] = Vb[(size_t)(t0 + ty + i * 8) * C_DIM + c0 + tx];
  __syncthreads();
#pragma unroll
  for (int i = 0; i < 4; ++i)
    Vtb[(size_t)(c0 + ty + i * 8) * T_SEQ + t0 + tx] = tile[tx][ty + i * 8];
}

// L[row] = sum over written Lpart entries (j < 2*(miR+1)); deterministic order.
__global__ void rowsum_k(const float* __restrict__ Lpart, float* __restrict__ Lr) {
  const int i = blockIdx.x * 256 + threadIdx.x;  // 64 blocks x 256 = 16384 rows
  const int jmax = (((i & 2047) >> 7) + 1) * 2;
  const float* p = Lpart + (size_t)i * 32;
  float s = 0.f;
  for (int j = 0; j < jmax; ++j) s += p[j];
  Lr[i] = s;
}

extern "C" void kernel_launch(void* const* d_in, const int* in_sizes, int n_in,
                              void* d_out, int out_size, void* d_ws, size_t ws_size,
                              hipStream_t stream) {
  (void)in_sizes; (void)n_in; (void)out_size; (void)ws_size;
  const float* x  = (const float*)d_in[0];
  const float* wq = (const float*)d_in[1];
  const float* wk = (const float*)d_in[2];
  const float* wv = (const float*)d_in[3];
  float* out = (float*)d_out;

  // Workspace layout (bytes); total 174,489,600 B (proven-safe bound)
  char* ws = (char*)d_ws;
  unsigned short* xb = (unsigned short*)(ws + 0);          // 16384x640 bf16
  float*          Lpart = (float*)(ws + 0);                // 16384x32 fp32, ALIASES xb
                                                            // (xb dead after gemm<0>)
  unsigned short* wb = (unsigned short*)(ws + 20971520);   // 3x640x640 bf16 (wq scaled)
  unsigned short* Qb = (unsigned short*)(ws + 23429120);   // Q,K,V contiguous bf16
  unsigned short* Vt = (unsigned short*)(ws + 86343680);   // 8x640x2048 bf16
  float*          Lr = (float*)(ws + 107315200);           // 16384 fp32 row sums
  unsigned short* Sb = (unsigned short*)(ws + 107380736);  // 8x2048x2048 bf16 (P)

  cast_x_k<<<2048, 256, 0, stream>>>(x, xb, 2621440);
  cast_w_k<<<dim3(400, 3), 256, 0, stream>>>(wq, wk, wv, wb);
  // QKV projections: 1920 linear blocks, XCD-swizzled, A-tile shared by 15 adjacent
  gemm_k<0><<<1920, 256, 0, stream>>>(xb, wb, Qb, nullptr, nullptr, nullptr, nullptr);
  transpose_v<<<dim3(64, 20, 8), dim3(32, 8), 0, stream>>>(Qb + (size_t)2 * 10485760, Vt);
  // P = exp(QK^T) causal (fused, unnormalized) + Lpart: 1088 blocks, batch per XCD
  gemm_k<1><<<1088, 256, 0, stream>>>(Qb, Qb + 10485760, Sb, nullptr, nullptr, nullptr,
                                      Lpart);
  rowsum_k<<<64, 256, 0, stream>>>(Lpart, Lr);
  // out = P Vt / L + x: 640 blocks, batch per XCD, heavy rows first
  gemm_k<2><<<640, 256, 0, stream>>>(Sb, Vt, nullptr, out, Lr, x, nullptr);
}

// Round 8
// 152.936 us; speedup vs baseline: 3.1819x; 1.1223x over previous
//
#include <hip/hip_runtime.h>
#include <stdint.h>
#include <stddef.h>

// Problem constants
#define T_SEQ 2048
#define C_DIM 640
#define N_BATCH 8

typedef __bf16 bf16x8 __attribute__((ext_vector_type(8)));
typedef float f32x4 __attribute__((ext_vector_type(4)));

__device__ __forceinline__ unsigned short f2bf(float f) {
  unsigned u = __float_as_uint(f);
  u += 0x7fffu + ((u >> 16) & 1u);   // round-to-nearest-even
  return (unsigned short)(u >> 16);
}
__device__ __forceinline__ float bf2f(unsigned short h) {
  return __uint_as_float(((unsigned)h) << 16);
}

__device__ __forceinline__ void gll16(const unsigned short* src, unsigned short* dst) {
  __builtin_amdgcn_global_load_lds(
      (const __attribute__((address_space(1))) void*)src,
      (__attribute__((address_space(3))) void*)dst, 16, 0, 0);
}

// Stage a 128(rows) x 64(k) bf16 tile into LDS (linear dest, row stride 128B).
// Global source pre-swizzled (rule #21) so swizzled ds_reads (byte ^= (row&7)<<4)
// observe logical data.
__device__ __forceinline__ void stage_tile(const unsigned short* gbase, int ldg,
                                           unsigned short* lbuf, int wave, int lane) {
#pragma unroll
  for (int i = 0; i < 4; ++i) {
    const int o   = i * 4096 + wave * 1024 + lane * 16;  // byte offset in tile
    const int row = o >> 7;
    const int cb  = o & 127;
    const int scb = cb ^ ((row & 7) << 4);               // involution within row
    const unsigned short* src = gbase + (size_t)row * ldg + (scb >> 1);
    unsigned short* dst = lbuf + ((i * 4096 + wave * 1024) >> 1);  // wave-uniform
    gll16(src, dst);
  }
}

// Decode t in [0,136) -> (mi, ni) with t = mi(mi+1)/2 + ni, ni<=mi.
__device__ __forceinline__ void tri_decode(int t, int& mi, int& ni) {
  int m = (int)((__fsqrt_rn(8.0f * (float)t + 1.0f) - 1.0f) * 0.5f);
  while ((m + 1) * (m + 2) / 2 <= t) ++m;
  while (m * (m + 1) / 2 > t) --m;
  mi = m;
  ni = t - m * (m + 1) / 2;
}

// One GEMM, four uses (all operands "row-major, K-contiguous" i.e. B^T layout):
// MODE 0: y = xb·Mt^T (bz==0) and V = xb·wv^T stored TRANSPOSED into Vt (bz==1).
//         Algebraic K-elimination: S = x·(Wq^T Wk/sqrtC)·x^T, so no Q/K needed.
// MODE 1: S=QK^T == y·xb^T per batch (causal tiles); epilogue: P=exp(S) masked,
//         bf16, + per-tile row sums Lpart. No max-subtraction (scores ~N(0,1)).
// MODE 2: out = P Vt^T / L + xb (residual from bf16 xb). A=P_b, B=Vt_b, fp32 out.
// MODE 3: Mt split-K partials: Mpart[bz] = wkT·wqT^T over K-chunk bz (128 wide).
// 128x128 tile, BK=64, 4 waves (2x2), mfma_f32_16x16x32_bf16, acc 4x4 frags/wave.
// Round-5 proven structure: double-buffered 64KB LDS, stage-next-then-compute,
// one barrier per K-step; 2 blocks/CU. (R6 proved forcing 5 blocks/CU spills;
// R7 proved single-buffer is not better at K=640.)
// Linear grid + XCD-chunk swizzle (T1); A-tile sharers adjacent.
template <int MODE>
__global__ __launch_bounds__(256) void gemm_k(
    const unsigned short* __restrict__ Abase, const unsigned short* __restrict__ Bbase,
    const unsigned short* __restrict__ B2base, unsigned short* __restrict__ OutB,
    unsigned short* __restrict__ OutB2, float* __restrict__ OutF,
    const float* __restrict__ Lrow, const unsigned short* __restrict__ Xres,
    float* __restrict__ Lpart) {
  const int lin = blockIdx.x;
  int mi, ni, bz;
  if constexpr (MODE == 0) {
    // nwg = 1280 = 8 * 160; logical wg = mi*10 + (z*5 + ni)
    const int wg = (lin & 7) * 160 + (lin >> 3);
    mi = wg / 10;
    const int t = wg % 10;
    bz = t / 5;            // z: 0 = y (via Mt), 1 = Vt (via wv)
    ni = t % 5;
  } else if constexpr (MODE == 1) {
    // nwg = 1088 = 8 * 136; XCD k == batch k
    const int wg = (lin & 7) * 136 + (lin >> 3);
    bz = wg / 136;
    tri_decode(wg % 136, mi, ni);
  } else if constexpr (MODE == 2) {
    // nwg = 640 = 8 * 80; heavy row-blocks (long K) dispatched first
    const int wg = (lin & 7) * 80 + (lin >> 3);
    bz = wg / 80;
    const int t = wg % 80;
    mi = 15 - t / 5;
    ni = t % 5;
  } else {
    // nwg = 125: bz = K-chunk (5 x 128), (mi,ni) in 5x5
    bz = lin / 25;
    const int rem = lin % 25;
    mi = rem / 5;
    ni = rem % 5;
  }

  __shared__ unsigned short As[2][8192];
  __shared__ unsigned short Bs[2][8192];
  const int tid = threadIdx.x;
  const int wave = tid >> 6, lane = tid & 63;
  const int wm = wave >> 1, wn = wave & 1;

  const unsigned short* Ap;
  const unsigned short* Bp;
  int ldA, ldB, ksteps;
  if constexpr (MODE == 0) {
    Ap = Abase + (size_t)mi * 81920;
    Bp = ((bz == 0) ? Bbase : B2base) + (size_t)ni * 81920;
    ldA = 640; ldB = 640; ksteps = 10;
  } else if constexpr (MODE == 1) {
    Ap = Abase + (size_t)bz * 1310720 + (size_t)mi * 81920;
    Bp = Bbase + (size_t)bz * 1310720 + (size_t)ni * 81920;
    ldA = 640; ldB = 640; ksteps = 10;
  } else if constexpr (MODE == 2) {
    Ap = Abase + (size_t)bz * 4194304 + (size_t)mi * 262144;
    Bp = Bbase + (size_t)bz * 1310720 + (size_t)ni * 262144;
    ldA = 2048; ldB = 2048; ksteps = 2 * (mi + 1);  // causal K bound
  } else {
    Ap = Abase + (size_t)mi * 81920 + bz * 128;
    Bp = Bbase + (size_t)ni * 81920 + bz * 128;
    ldA = 640; ldB = 640; ksteps = 2;
  }

  f32x4 acc[4][4] = {};

  stage_tile(Ap, ldA, As[0], wave, lane);
  stage_tile(Bp, ldB, Bs[0], wave, lane);
  __syncthreads();

  int cur = 0;
  for (int t = 0; t < ksteps; ++t) {
    if (t + 1 < ksteps) {  // issue next-tile loads BEFORE compute (T3-min)
      stage_tile(Ap + (size_t)(t + 1) * 64, ldA, As[cur ^ 1], wave, lane);
      stage_tile(Bp + (size_t)(t + 1) * 64, ldB, Bs[cur ^ 1], wave, lane);
    }
#pragma unroll
    for (int kk = 0; kk < 2; ++kk) {
      bf16x8 af[4], bfr[4];
#pragma unroll
      for (int mt = 0; mt < 4; ++mt) {
        const int row = wm * 64 + mt * 16 + (lane & 15);
        const int cb  = kk * 64 + ((lane >> 4) << 4);
        af[mt] = *(const bf16x8*)&As[cur][row * 64 + ((cb ^ ((row & 7) << 4)) >> 1)];
      }
#pragma unroll
      for (int nt = 0; nt < 4; ++nt) {
        const int row = wn * 64 + nt * 16 + (lane & 15);
        const int cb  = kk * 64 + ((lane >> 4) << 4);
        bfr[nt] = *(const bf16x8*)&Bs[cur][row * 64 + ((cb ^ ((row & 7) << 4)) >> 1)];
      }
#pragma unroll
      for (int mt = 0; mt < 4; ++mt)
#pragma unroll
        for (int nt = 0; nt < 4; ++nt)
          acc[mt][nt] = __builtin_amdgcn_mfma_f32_16x16x32_bf16(af[mt], bfr[nt],
                                                                acc[mt][nt], 0, 0, 0);
    }
    __syncthreads();  // drains vmcnt (staged tile ready) + protects buffer reuse
    cur ^= 1;
  }

  // Epilogue. C/D frag: col = lane&15, row = (lane>>4)*4 + r  [m89/m91-verified]
  if constexpr (MODE == 1) {
    // P = exp(S) with causal mask; per-row partial sums -> Lpart[row][ni*2+wn].
#pragma unroll
    for (int mt = 0; mt < 4; ++mt) {
      const int r0 = wm * 64 + mt * 16 + ((lane >> 4) << 2);
      const int grow = mi * 128 + r0;
      float rsum[4] = {0.f, 0.f, 0.f, 0.f};
#pragma unroll
      for (int nt = 0; nt < 4; ++nt) {
        const int gc = ni * 128 + wn * 64 + nt * 16 + (lane & 15);
        const size_t base = (size_t)bz * 4194304 + (size_t)grow * 2048 + gc;
#pragma unroll
        for (int r = 0; r < 4; ++r) {
          const float e = (gc <= grow + r) ? __expf(acc[mt][nt][r]) : 0.0f;
          OutB[base + (size_t)r * 2048] = f2bf(e);
          rsum[r] += e;
        }
      }
#pragma unroll
      for (int off = 1; off < 16; off <<= 1) {
#pragma unroll
        for (int r = 0; r < 4; ++r) rsum[r] += __shfl_xor(rsum[r], off);
      }
      if ((lane & 15) == 0) {
#pragma unroll
        for (int r = 0; r < 4; ++r)
          Lpart[((size_t)bz * 2048 + grow + r) * 32 + ni * 2 + wn] = rsum[r];
      }
    }
  } else {
#pragma unroll
    for (int mt = 0; mt < 4; ++mt) {
#pragma unroll
      for (int nt = 0; nt < 4; ++nt) {
        const int r0 = wm * 64 + mt * 16 + ((lane >> 4) << 2);
        const int c  = wn * 64 + nt * 16 + (lane & 15);
        if constexpr (MODE == 0) {
          if (bz == 0) {  // y, row-major
            const size_t base = (size_t)(mi * 128 + r0) * 640 + ni * 128 + c;
#pragma unroll
            for (int r = 0; r < 4; ++r) OutB[base + (size_t)r * 640] = f2bf(acc[mt][nt][r]);
          } else {        // V, stored transposed into Vt[b][c][t]
            const int b = mi >> 4;
            const int tloc = ((mi & 15) << 7) + r0;  // multiple of 4 -> 8B aligned
            const int gc = ni * 128 + c;
            ushort4 o4;
            o4.x = f2bf(acc[mt][nt][0]); o4.y = f2bf(acc[mt][nt][1]);
            o4.z = f2bf(acc[mt][nt][2]); o4.w = f2bf(acc[mt][nt][3]);
            *(ushort4*)&OutB2[(size_t)b * 1310720 + (size_t)gc * 2048 + tloc] = o4;
          }
        } else if constexpr (MODE == 2) {
          const int grow = mi * 128 + r0;
          const size_t base = (size_t)bz * 1310720 + (size_t)grow * 640 + ni * 128 + c;
#pragma unroll
          for (int r = 0; r < 4; ++r) {
            const float l = Lrow[(size_t)bz * 2048 + grow + r];
            OutF[base + (size_t)r * 640] =
                acc[mt][nt][r] / l + bf2f(Xres[base + (size_t)r * 640]);
          }
        } else {  // MODE 3: fp32 partials
          const size_t base = (size_t)bz * 409600 + (size_t)(mi * 128 + r0) * 640 + ni * 128 + c;
#pragma unroll
          for (int r = 0; r < 4; ++r) OutF[base + (size_t)r * 640] = acc[mt][nt][r];
        }
      }
    }
  }
}

__global__ void cast_x_k(const float* __restrict__ x, unsigned short* __restrict__ xb, int n4) {
  const int stride = gridDim.x * blockDim.x;
  for (int i = blockIdx.x * blockDim.x + threadIdx.x; i < n4; i += stride) {
    const float4 v = ((const float4*)x)[i];
    ushort4 o;
    o.x = f2bf(v.x); o.y = f2bf(v.y); o.z = f2bf(v.z); o.w = f2bf(v.w);
    ((ushort4*)xb)[i] = o;
  }
}

// z==0: wq -> wqT (transposed, scaled by 1/sqrt(640)); z==1: wk -> wkT
// (transposed); z==2: wv -> wvb (plain cast). All bf16 out.
__global__ void tcast_w(const float* __restrict__ wq, const float* __restrict__ wk,
                        const float* __restrict__ wv, unsigned short* __restrict__ wqT,
                        unsigned short* __restrict__ wkT, unsigned short* __restrict__ wvb) {
  const int z = blockIdx.y;
  const int tx = threadIdx.x, ty = threadIdx.y;
  if (z == 2) {
    const int e = (blockIdx.x * 256 + ty * 32 + tx) * 4;  // 400*256*4 = 409600
    const float4 v = *(const float4*)&wv[e];
    ushort4 o;
    o.x = f2bf(v.x); o.y = f2bf(v.y); o.z = f2bf(v.z); o.w = f2bf(v.w);
    *(ushort4*)&wvb[e] = o;
    return;
  }
  __shared__ float tile[32][33];
  const float* w = (z == 0) ? wq : wk;
  unsigned short* wT = (z == 0) ? wqT : wkT;
  const float s = (z == 0) ? 0.03952847075210474f : 1.0f;  // 1/sqrt(640)
  const int bo = (blockIdx.x / 20) * 32, bc = (blockIdx.x % 20) * 32;
#pragma unroll
  for (int i = 0; i < 4; ++i)
    tile[ty + i * 8][tx] = w[(size_t)(bo + ty + i * 8) * 640 + bc + tx];
  __syncthreads();
#pragma unroll
  for (int i = 0; i < 4; ++i)
    wT[(size_t)(bc + ty + i * 8) * 640 + bo + tx] = f2bf(tile[tx][ty + i * 8] * s);
}

// Mt[e] = bf16(sum_p Mpart[p][e]), vectorized x4. 400 blocks x 256 threads.
__global__ void reduce_mt(const float* __restrict__ Mpart, unsigned short* __restrict__ Mt) {
  const int e = (blockIdx.x * 256 + threadIdx.x) * 4;
  float4 a = *(const float4*)&Mpart[e];
#pragma unroll
  for (int p = 1; p < 5; ++p) {
    const float4 b = *(const float4*)&Mpart[(size_t)p * 409600 + e];
    a.x += b.x; a.y += b.y; a.z += b.z; a.w += b.w;
  }
  ushort4 o;
  o.x = f2bf(a.x); o.y = f2bf(a.y); o.z = f2bf(a.z); o.w = f2bf(a.w);
  *(ushort4*)&Mt[e] = o;
}

// L[row] = sum over written Lpart entries (j < 2*(miR+1)); deterministic order.
__global__ void rowsum_k(const float* __restrict__ Lpart, float* __restrict__ Lr) {
  const int i = blockIdx.x * 256 + threadIdx.x;  // 64 blocks x 256 = 16384 rows
  const int jmax = (((i & 2047) >> 7) + 1) * 2;
  const float* p = Lpart + (size_t)i * 32;
  float s = 0.f;
  for (int j = 0; j < jmax; ++j) s += p[j];
  Lr[i] = s;
}

extern "C" void kernel_launch(void* const* d_in, const int* in_sizes, int n_in,
                              void* d_out, int out_size, void* d_ws, size_t ws_size,
                              hipStream_t stream) {
  (void)in_sizes; (void)n_in; (void)out_size; (void)ws_size;
  const float* x  = (const float*)d_in[0];
  const float* wq = (const float*)d_in[1];
  const float* wk = (const float*)d_in[2];
  const float* wv = (const float*)d_in[3];
  float* out = (float*)d_out;

  // Workspace layout (bytes); total 143,654,912 (< 174,489,600 proven-safe)
  char* ws = (char*)d_ws;
  unsigned short* xb  = (unsigned short*)(ws + 0);         // 16384x640 bf16 (live to end)
  unsigned short* wqT = (unsigned short*)(ws + 20971520);  // 640x640 bf16, scaled
  unsigned short* wkT = (unsigned short*)(ws + 21790720);  // 640x640 bf16
  unsigned short* wvb = (unsigned short*)(ws + 22609920);  // 640x640 bf16
  unsigned short* Mt  = (unsigned short*)(ws + 23429120);  // 640x640 bf16 = Wk^T Wq /sqrtC
  unsigned short* y   = (unsigned short*)(ws + 24248320);  // 16384x640 bf16
  unsigned short* Vt  = (unsigned short*)(ws + 45219840);  // 8x640x2048 bf16
  float*          Mpart = (float*)(ws + 66191360);         // 5x640x640 fp32
  float*          Lpart = (float*)(ws + 74383360);         // 16384x32 fp32
  float*          Lr  = (float*)(ws + 76480512);           // 16384 fp32
  unsigned short* Sb  = (unsigned short*)(ws + 76546048);  // 8x2048x2048 bf16 (P)

  cast_x_k<<<2048, 256, 0, stream>>>(x, xb, 2621440);
  tcast_w<<<dim3(400, 3), dim3(32, 8), 0, stream>>>(wq, wk, wv, wqT, wkT, wvb);
  // Mt partials: 125 blocks (split-K to dodge small-grid latency), fp32
  gemm_k<3><<<125, 256, 0, stream>>>(wkT, wqT, nullptr, nullptr, nullptr, Mpart,
                                     nullptr, nullptr, nullptr);
  reduce_mt<<<400, 256, 0, stream>>>(Mpart, Mt);
  // y = xb Mt^T and Vt (V fused-transposed): 1280 blocks, XCD-swizzled
  gemm_k<0><<<1280, 256, 0, stream>>>(xb, Mt, wvb, y, Vt, nullptr, nullptr, nullptr,
                                      nullptr);
  // P = exp(y xb^T) causal + Lpart: 1088 blocks, batch per XCD
  gemm_k<1><<<1088, 256, 0, stream>>>(y, xb, nullptr, Sb, nullptr, nullptr, nullptr,
                                      nullptr, Lpart);
  rowsum_k<<<64, 256, 0, stream>>>(Lpart, Lr);
  // out = P Vt / L + xb: 640 blocks, batch per XCD, heavy rows first
  gemm_k<2><<<640, 256, 0, stream>>>(Sb, Vt, nullptr, nullptr, nullptr, out, Lr, xb,
                                     nullptr);
}